// Round 4
// baseline (299.896 us; speedup 1.0000x reference)
//
#include <hip/hip_runtime.h>
#include <hip/hip_bf16.h>
#include <stdint.h>

#define BATCH 4096
#define TLEN  1024
#define NF_IT 171        // forward triple iters: steps 1..513
#define NB_IT 170        // backward triple iters: steps 514..1023
#define MSTR  72         // LDS matrix row stride (elements); 144B, 16B-aligned
#define PSTR  72

typedef short bf16x8 __attribute__((ext_vector_type(8)));
typedef float f32x4  __attribute__((ext_vector_type(4)));

// ---- LDS layout (bytes). Matrices [64][MSTR] bf16 = 9216 B each ----
#define OFF_S0    0        // T0 plain
#define OFF_S1    9216     // T1 plain
#define OFF_G0    18432    // T0 transposed
#define OFF_G1    27648    // T1 transposed
#define OFF_RT    18432    // triple transposed (aliases G0, G dead)
#define OFF_RP    27648    // triple plain      (aliases G1)
#define OFF_W     36864    // 4 pair-products, 4*9216 -> ends 73728
#define OFF_PE    73728    // float pE[2][64]
#define OFF_PIV   74240    // float piv[64]
// loop-phase region aliases W (dead after triple build):
#define OFF_PF    36864    // bf16 Pf[16][PSTR]  (fwd alpha)
#define OFF_PB    39168    // bf16 Pb[16][PSTR]  (bwd beta)
#define OFF_YSF   41472    // u64 ysf[11][16]
#define OFF_YSB   42880    // u64 ysb[11][16]
#define OFF_YBALL 44288    // u64 yball[16][16]
#define OFF_LACCF 46336    // float[16]
#define OFF_LACCB 46400    // float[16]
#define SMEM_SZ   74496

#define MFMA(a,b,c) __builtin_amdgcn_mfma_f32_16x16x32_bf16(a,b,c,0,0,0)

// ---------------------------------------------------------------------------
// 256 wgs x 128 thr (2 waves). Wave 0 = forward chain, wave 1 = backward
// chain; each wave does the FULL 64-state update for 16 batch rows with all
// A-frags (8 candidates x 4 tiles x 2 K-halves = 256 VGPRs) in registers and
// a wave-private LDS alpha buffer. No __syncthreads in the main loop.
// ---------------------------------------------------------------------------
__global__ __launch_bounds__(128, 1) void hmm_fused(
    const int* __restrict__ y, const float* __restrict__ Tmat,
    const float* __restrict__ Emat, const float* __restrict__ Pi,
    float* __restrict__ out)
{
    __shared__ __align__(16) unsigned char SM[SMEM_SZ];

    const int tid  = threadIdx.x;
    const int wv   = tid >> 6;          // 0 = fwd, 1 = bwd
    const int lane = tid & 63;
    const int lr   = lane & 15;
    const int g    = lane >> 4;
    const int bcol = lr;                // batch column within block
    const int R0   = blockIdx.x * 16;
    const bool is_fwd = (wv == 0);

    float* pE  = (float*)(SM + OFF_PE);
    float* piv = (float*)(SM + OFF_PIV);
    const f32x4 zero = {0.f, 0.f, 0.f, 0.f};

    // ---- phase 0: emission + pi softmax (wave 0) ----
    if (tid < 64) {
        const float e0 = Emat[tid*2+0], e1 = Emat[tid*2+1];
        const float em = fmaxf(e0, e1);
        const float p0 = __expf(e0-em), p1 = __expf(e1-em);
        const float ez = 1.0f / (p0 + p1);
        pE[tid]      = p0 * ez;
        pE[64 + tid] = p1 * ez;
        float v = Pi[tid];
        float mx = v;
        #pragma unroll
        for (int d = 1; d < 64; d <<= 1) mx = fmaxf(mx, __shfl_xor(mx, d));
        const float e = __expf(v - mx);
        float z = e;
        #pragma unroll
        for (int d = 1; d < 64; d <<= 1) z += __shfl_xor(z, d);
        piv[tid] = e / z;
    }
    __syncthreads();

    // ---- phase 1: row-softmax of T + emission fold; plain + transposed ----
    {
        const int r = tid >> 1;           // 0..63
        const int h = tid & 1;            // half: cols h*32..h*32+31
        float v[32];
        #pragma unroll
        for (int q = 0; q < 8; q++) {
            const float4 t4 = *(const float4*)(Tmat + r*64 + h*32 + q*4);
            v[q*4+0]=t4.x; v[q*4+1]=t4.y; v[q*4+2]=t4.z; v[q*4+3]=t4.w;
        }
        float mx = v[0];
        #pragma unroll
        for (int k = 1; k < 32; k++) mx = fmaxf(mx, v[k]);
        mx = fmaxf(mx, __shfl_xor(mx, 1));
        float z = 0.f;
        #pragma unroll
        for (int k = 0; k < 32; k++) { v[k] = __expf(v[k]-mx); z += v[k]; }
        z += __shfl_xor(z, 1);
        const float inv = 1.0f / z;
        __hip_bfloat16* S0 = (__hip_bfloat16*)(SM + OFF_S0);
        __hip_bfloat16* S1 = (__hip_bfloat16*)(SM + OFF_S1);
        __hip_bfloat16* G0 = (__hip_bfloat16*)(SM + OFF_G0);
        __hip_bfloat16* G1 = (__hip_bfloat16*)(SM + OFF_G1);
        #pragma unroll
        for (int k = 0; k < 32; k++) {
            const int j = h*32 + k;
            const float t = v[k] * inv;
            const __hip_bfloat16 h0 = __float2bfloat16(t * pE[j]);
            const __hip_bfloat16 h1 = __float2bfloat16(t * pE[64 + j]);
            S0[r*MSTR + j] = h0;  S1[r*MSTR + j] = h1;
            G0[j*MSTR + r] = h0;  G1[j*MSTR + r] = h1;
        }
    }
    __syncthreads();

    // ---- phase 2: W_c[x][y] = (T_b2*T_b3)[y][x]; wave wv does c=2wv,2wv+1 ----
    #pragma unroll
    for (int cc = 0; cc < 2; cc++) {
        const int c  = wv*2 + cc;
        const int b2 = c >> 1, b3 = c & 1;
        const __hip_bfloat16* X = (const __hip_bfloat16*)(SM + (b3 ? OFF_G1 : OFF_G0));
        const __hip_bfloat16* V = (const __hip_bfloat16*)(SM + (b2 ? OFF_S1 : OFF_S0));
        __hip_bfloat16* W = (__hip_bfloat16*)(SM + OFF_W) + c*(64*MSTR);
        #pragma unroll
        for (int xt = 0; xt < 4; xt++) {
            const bf16x8 a0 = *(const bf16x8*)(X + (xt*16+lr)*MSTR + g*8);
            const bf16x8 a1 = *(const bf16x8*)(X + (xt*16+lr)*MSTR + 32 + g*8);
            #pragma unroll
            for (int yb = 0; yb < 4; yb++) {
                const bf16x8 b0 = *(const bf16x8*)(V + (yb*16+lr)*MSTR + g*8);
                const bf16x8 b1 = *(const bf16x8*)(V + (yb*16+lr)*MSTR + 32 + g*8);
                f32x4 d = MFMA(a0, b0, zero);
                d = MFMA(a1, b1, d);
                const int ycol = yb*16 + lr, xb = xt*16 + g*4;
                W[(xb+0)*MSTR + ycol] = __float2bfloat16(d.x);
                W[(xb+1)*MSTR + ycol] = __float2bfloat16(d.y);
                W[(xb+2)*MSTR + ycol] = __float2bfloat16(d.z);
                W[(xb+3)*MSTR + ycol] = __float2bfloat16(d.w);
            }
        }
    }
    __syncthreads();

    // ---- phase 3: triples R_m = T_b1*(T_b2 T_b3); keep ALL frags in regs ----
    bf16x8 Afr[8][4][2];
    {
        __hip_bfloat16* Rt = (__hip_bfloat16*)(SM + OFF_RT);
        __hip_bfloat16* Rp = (__hip_bfloat16*)(SM + OFF_RP);
        #pragma unroll
        for (int m = 0; m < 8; m++) {
            const int b1 = m >> 2, c = m & 3;
            const __hip_bfloat16* X = (const __hip_bfloat16*)(SM + OFF_W) + c*(64*MSTR);
            const __hip_bfloat16* V = (const __hip_bfloat16*)(SM + (b1 ? OFF_S1 : OFF_S0));
            #pragma unroll
            for (int tt = 0; tt < 8; tt++) {
                const int t8 = wv*8 + tt;
                const int xt = t8 >> 2, yb = t8 & 3;
                const bf16x8 a0 = *(const bf16x8*)(X + (xt*16+lr)*MSTR + g*8);
                const bf16x8 a1 = *(const bf16x8*)(X + (xt*16+lr)*MSTR + 32 + g*8);
                const bf16x8 b0 = *(const bf16x8*)(V + (yb*16+lr)*MSTR + g*8);
                const bf16x8 b1 = *(const bf16x8*)(V + (yb*16+lr)*MSTR + 32 + g*8);
                f32x4 d = MFMA(a0, b0, zero);
                d = MFMA(a1, b1, d);
                const int ycol = yb*16 + lr, xb = xt*16 + g*4;
                Rt[(xb+0)*MSTR + ycol] = __float2bfloat16(d.x);
                Rt[(xb+1)*MSTR + ycol] = __float2bfloat16(d.y);
                Rt[(xb+2)*MSTR + ycol] = __float2bfloat16(d.z);
                Rt[(xb+3)*MSTR + ycol] = __float2bfloat16(d.w);
                union { __hip_bfloat16 hh[4]; uint2 u; } pk;
                pk.hh[0] = __float2bfloat16(d.x);
                pk.hh[1] = __float2bfloat16(d.y);
                pk.hh[2] = __float2bfloat16(d.z);
                pk.hh[3] = __float2bfloat16(d.w);
                *(uint2*)(Rp + ycol*MSTR + xb) = pk.u;
            }
            __syncthreads();
            {
                const __hip_bfloat16* RA = is_fwd ? Rt : Rp;
                #pragma unroll
                for (int t = 0; t < 4; t++) {
                    Afr[m][t][0] = *(const bf16x8*)(RA + (t*16+lr)*MSTR + g*8);
                    Afr[m][t][1] = *(const bf16x8*)(RA + (t*16+lr)*MSTR + 32 + g*8);
                }
            }
            __syncthreads();
        }
    }

    // ---- phase 4: ballot-pack y; each wave builds its own nibble stream ----
    unsigned long long* yball = (unsigned long long*)(SM + OFF_YBALL);
    #pragma unroll
    for (int q = 0; q < 8; q++) {
        const int row = wv*8 + q;
        const int* yr = y + (size_t)(R0 + row) * TLEN;
        #pragma unroll
        for (int w = 0; w < 16; w++) {
            const unsigned long long bal = __ballot(yr[w*64 + lane] != 0);
            if (lane == 0) yball[row*16 + w] = bal;
        }
    }
    __syncthreads();
    unsigned long long* ys = (unsigned long long*)(SM + (is_fwd ? OFF_YSF : OFF_YSB));
    {
        const int c = lane & 15;
        #pragma unroll
        for (int pass = 0; pass < 3; pass++) {
            const int slot = pass*4 + (lane >> 4);
            if (slot < 11) {
                unsigned long long wd = 0ull;
                if (is_fwd) {
                    for (int n = 0; n < 16; n++) {
                        const int i = slot*16 + n;
                        if (i < NF_IT) {
                            const int t1 = 3*i + 1;
                            const unsigned long long bA = (yball[c*16 + (t1>>6)] >> (t1 & 63)) & 1ull;
                            const unsigned long long bB = (yball[c*16 + ((t1+1)>>6)] >> ((t1+1) & 63)) & 1ull;
                            const unsigned long long bC = (yball[c*16 + ((t1+2)>>6)] >> ((t1+2) & 63)) & 1ull;
                            wd |= ((bA<<2) | (bB<<1) | bC) << (4*n);
                        }
                    }
                } else {
                    for (int n = 0; n < 16; n++) {
                        const int jj = slot*16 + n;
                        if (jj < NB_IT) {
                            const int t = 1021 - 3*jj;
                            const unsigned long long bA = (yball[c*16 + (t>>6)] >> (t & 63)) & 1ull;
                            const unsigned long long bB = (yball[c*16 + ((t+1)>>6)] >> ((t+1) & 63)) & 1ull;
                            const unsigned long long bC = (yball[c*16 + ((t+2)>>6)] >> ((t+2) & 63)) & 1ull;
                            wd |= ((bA<<2) | (bB<<1) | bC) << (4*n);
                        }
                    }
                }
                ys[slot*16 + c] = wd;
            }
        }
    }

    // ---- phase 5: init wave-private P + running column sum Sw ----
    __hip_bfloat16* P = (__hip_bfloat16*)(SM + (is_fwd ? OFF_PF : OFF_PB));
    float Sw;
    {
        if (is_fwd) {
            const int y0 = y[(size_t)(R0 + bcol) * TLEN];
            const float* pe = pE + y0*64;
            float part = 0.f;
            #pragma unroll
            for (int k = 0; k < 16; k++) {
                const int s = g*16 + k;
                const float v = piv[s] * pe[s];
                P[bcol*PSTR + s] = __float2bfloat16(v);
                part += v;
            }
            part += __shfl_xor(part, 16);
            part += __shfl_xor(part, 32);
            Sw = part;
        } else {
            #pragma unroll
            for (int k = 0; k < 16; k++)
                P[bcol*PSTR + g*16 + k] = __float2bfloat16(1.0f);
            Sw = 64.0f;
        }
    }

    // ---- phase 6: barrier-free main loop ----
    float lacc = 0.f;
    unsigned long long yw = 0ull;
    const int nit = is_fwd ? NF_IT : NB_IT;

    for (int j = 0; j < nit; j++) {
        if ((j & 15) == 0) yw = ys[(j>>4)*16 + bcol];
        const int idx = (int)(yw & 7ull);
        yw >>= 4;

        const __hip_bfloat16* prow = P + bcol*PSTR;
        const bf16x8 B0 = *(const bf16x8*)(prow + g*8);
        const bf16x8 B1 = *(const bf16x8*)(prow + 32 + g*8);

        const float rs = __builtin_amdgcn_rcpf(Sw);
        lacc += __logf(Sw);

        const bool s1b = idx & 1;
        const int  mhi = idx >> 1;
        f32x4 sel0, sel1, sel2, sel3;
        #pragma unroll
        for (int mp = 0; mp < 4; mp++) {
            f32x4 a0 = MFMA(Afr[2*mp][0][0], B0, zero);
            f32x4 a1 = MFMA(Afr[2*mp][1][0], B0, zero);
            f32x4 a2 = MFMA(Afr[2*mp][2][0], B0, zero);
            f32x4 a3 = MFMA(Afr[2*mp][3][0], B0, zero);
            a0 = MFMA(Afr[2*mp][0][1], B1, a0);
            a1 = MFMA(Afr[2*mp][1][1], B1, a1);
            a2 = MFMA(Afr[2*mp][2][1], B1, a2);
            a3 = MFMA(Afr[2*mp][3][1], B1, a3);
            f32x4 c0 = MFMA(Afr[2*mp+1][0][0], B0, zero);
            f32x4 c1 = MFMA(Afr[2*mp+1][1][0], B0, zero);
            f32x4 c2 = MFMA(Afr[2*mp+1][2][0], B0, zero);
            f32x4 c3 = MFMA(Afr[2*mp+1][3][0], B0, zero);
            c0 = MFMA(Afr[2*mp+1][0][1], B1, c0);
            c1 = MFMA(Afr[2*mp+1][1][1], B1, c1);
            c2 = MFMA(Afr[2*mp+1][2][1], B1, c2);
            c3 = MFMA(Afr[2*mp+1][3][1], B1, c3);
            const f32x4 p0 = s1b ? c0 : a0;
            const f32x4 p1 = s1b ? c1 : a1;
            const f32x4 p2 = s1b ? c2 : a2;
            const f32x4 p3 = s1b ? c3 : a3;
            if (mp == 0) { sel0 = p0; sel1 = p1; sel2 = p2; sel3 = p3; }
            else {
                const bool gm = (mhi == mp);
                sel0 = gm ? p0 : sel0;
                sel1 = gm ? p1 : sel1;
                sel2 = gm ? p2 : sel2;
                sel3 = gm ? p3 : sel3;
            }
        }

        // scale by 1/S_prev (deferred renorm), write back, new column sum
        sel0 *= rs; sel1 *= rs; sel2 *= rs; sel3 *= rs;

        union { __hip_bfloat162 h2[2]; uint2 u; } pk;
        pk.h2[0] = __float22bfloat162_rn(make_float2(sel0.x, sel0.y));
        pk.h2[1] = __float22bfloat162_rn(make_float2(sel0.z, sel0.w));
        *(uint2*)(P + bcol*PSTR + 0*16 + g*4) = pk.u;
        pk.h2[0] = __float22bfloat162_rn(make_float2(sel1.x, sel1.y));
        pk.h2[1] = __float22bfloat162_rn(make_float2(sel1.z, sel1.w));
        *(uint2*)(P + bcol*PSTR + 1*16 + g*4) = pk.u;
        pk.h2[0] = __float22bfloat162_rn(make_float2(sel2.x, sel2.y));
        pk.h2[1] = __float22bfloat162_rn(make_float2(sel2.z, sel2.w));
        *(uint2*)(P + bcol*PSTR + 2*16 + g*4) = pk.u;
        pk.h2[0] = __float22bfloat162_rn(make_float2(sel3.x, sel3.y));
        pk.h2[1] = __float22bfloat162_rn(make_float2(sel3.z, sel3.w));
        *(uint2*)(P + bcol*PSTR + 3*16 + g*4) = pk.u;

        float p = (sel0.x + sel0.y + sel0.z + sel0.w)
                + (sel1.x + sel1.y + sel1.z + sel1.w)
                + (sel2.x + sel2.y + sel2.z + sel2.w)
                + (sel3.x + sel3.y + sel3.z + sel3.w);
        p += __shfl_xor(p, 16);
        p += __shfl_xor(p, 32);
        Sw = p;
    }

    // ---- epilogue: logprob[b] = laccF + laccB + log(Pf[b,:] . Pb[b,:]) ----
    if (lane < 16)
        ((float*)(SM + (is_fwd ? OFF_LACCF : OFF_LACCB)))[lane] = lacc;
    __syncthreads();
    if (wv == 0) {
        const __hip_bfloat16* Pf = (const __hip_bfloat16*)(SM + OFF_PF);
        const __hip_bfloat16* Pb = (const __hip_bfloat16*)(SM + OFF_PB);
        float dot = 0.f;
        #pragma unroll
        for (int k = 0; k < 16; k++) {
            const int s = g*16 + k;
            dot += __bfloat162float(Pf[bcol*PSTR + s]) * __bfloat162float(Pb[bcol*PSTR + s]);
        }
        dot += __shfl_xor(dot, 16);
        dot += __shfl_xor(dot, 32);
        float lp = ((float*)(SM + OFF_LACCF))[bcol]
                 + ((float*)(SM + OFF_LACCB))[bcol] + __logf(dot);
        lp += __shfl_xor(lp, 1);
        lp += __shfl_xor(lp, 2);
        lp += __shfl_xor(lp, 4);
        lp += __shfl_xor(lp, 8);
        if (tid == 0) atomicAdd(out, lp * (1.0f / BATCH));
    }
}

// ---------------------------------------------------------------------------
extern "C" void kernel_launch(void* const* d_in, const int* in_sizes, int n_in,
                              void* d_out, int out_size, void* d_ws, size_t ws_size,
                              hipStream_t stream) {
    const int*   y  = (const int*)  d_in[0];
    const float* T  = (const float*)d_in[1];
    const float* E  = (const float*)d_in[2];
    const float* Pi = (const float*)d_in[3];
    float* out = (float*)d_out;

    hipMemsetAsync(out, 0, sizeof(float), stream);
    hipLaunchKernelGGL(hmm_fused, dim3(BATCH/16), dim3(128), 0, stream, y, T, E, Pi, out);
}

// Round 5
// 183.508 us; speedup vs baseline: 1.6342x; 1.6342x over previous
//
#include <hip/hip_runtime.h>
#include <hip/hip_bf16.h>
#include <stdint.h>

#define BATCH 4096
#define TLEN  1024
#define NF_IT 171        // forward triple iters: steps 1..513
#define NB_IT 170        // backward triple iters: steps 1023 down to 514
#define MSTR  72         // LDS matrix row stride (elements); 144B, 16B-aligned
#define PSTR  72

typedef short bf16x8 __attribute__((ext_vector_type(8)));
typedef float f32x4  __attribute__((ext_vector_type(4)));

// ---- LDS layout (bytes). Matrices [64][MSTR] bf16 = 9216 B each ----
#define OFF_S0   0         // T0 plain (emission-folded)
#define OFF_S1   9216      // T1 plain
#define OFF_G0   18432     // T0 transposed
#define OFF_G1   27648     // T1 transposed
#define OFF_R    18432     // triple scratch, one matrix at a time (aliases G0; G dead)
#define OFF_W    36864     // 4 pair-products (transposed form), 4*9216 -> ends 73728
#define OFF_PE   73728     // float pE[2][64]
#define OFF_PIV  74240     // float piv[64]
// loop-phase region aliases W (dead after triple build):
#define OFF_P     36864    // bf16 P[2][16][PSTR] = 4608
#define OFF_YS    41472    // u64 ys[11][16] = 1408
#define OFF_YBALL 42880    // u64 yball[16][16] = 2048
#define OFF_PART  44928    // float part[4][16] = 256
#define SMEM_SZ   74496

// ---- d_ws layout (bytes), total 1081344 ----
#define WS_AM 0            // bf16 alpha_mid[4096][64]
#define WS_BM 524288       // bf16 beta_mid [4096][64]
#define WS_LF 1048576      // f32 laccF[4096]
#define WS_LB 1064960      // f32 laccB[4096]

#define MFMA(a,b,c) __builtin_amdgcn_mfma_f32_16x16x32_bf16(a,b,c,0,0,0)

// ---------------------------------------------------------------------------
// 512 wgs x 256 thr (4 waves). wg = (direction, 16-batch-block): even blocks
// forward, odd backward. Wave wv owns state tile [16wv,16wv+16); holds all
// 8 triple-candidate A-frags (16 bf16x8 = 64 VGPRs) in registers. Per iter:
// 16 MFMA + 28-cndmask select; renorm every 4th iter (deferred). Independent
// 4-wave barrier per wg (no fwd/bwd lockstep). Mid-state to ws; epilogue
// kernel combines.
// ---------------------------------------------------------------------------
__global__ __launch_bounds__(256, 2) void hmm_chain(
    const int* __restrict__ y, const float* __restrict__ Tmat,
    const float* __restrict__ Emat, const float* __restrict__ Pi,
    unsigned char* __restrict__ ws)
{
    __shared__ __align__(16) unsigned char SM[SMEM_SZ];

    const int tid  = threadIdx.x;
    const int wv   = tid >> 6;          // state tile 0..3
    const int lane = tid & 63;
    const int lr   = lane & 15;         // MFMA row/col lane index (= batch col in loop)
    const int g    = lane >> 4;         // k-group
    const int dir  = blockIdx.x & 1;    // 0 = fwd, 1 = bwd
    const int blk  = blockIdx.x >> 1;
    const int R0   = blk * 16;
    const bool is_fwd = (dir == 0);

    float* pE  = (float*)(SM + OFF_PE);
    float* piv = (float*)(SM + OFF_PIV);
    const f32x4 zero = {0.f, 0.f, 0.f, 0.f};

    // ---- phase 0: emission + pi softmax ----
    if (tid < 64) {
        const float e0 = Emat[tid*2+0], e1 = Emat[tid*2+1];
        const float em = fmaxf(e0, e1);
        const float p0 = __expf(e0-em), p1 = __expf(e1-em);
        const float ez = 1.0f / (p0 + p1);
        pE[tid]      = p0 * ez;
        pE[64 + tid] = p1 * ez;
        float v = Pi[tid];
        float mx = v;
        #pragma unroll
        for (int d = 1; d < 64; d <<= 1) mx = fmaxf(mx, __shfl_xor(mx, d));
        const float e = __expf(v - mx);
        float z = e;
        #pragma unroll
        for (int d = 1; d < 64; d <<= 1) z += __shfl_xor(z, d);
        piv[tid] = e / z;
    }
    __syncthreads();

    // ---- phase 1: row-softmax of T + emission fold; plain + transposed ----
    {
        const int r  = tid >> 2;          // 0..63
        const int q4 = tid & 3;           // 16 cols each
        float v[16];
        #pragma unroll
        for (int q = 0; q < 4; q++) {
            const float4 t4 = *(const float4*)(Tmat + r*64 + q4*16 + q*4);
            v[q*4+0]=t4.x; v[q*4+1]=t4.y; v[q*4+2]=t4.z; v[q*4+3]=t4.w;
        }
        float mx = v[0];
        #pragma unroll
        for (int k = 1; k < 16; k++) mx = fmaxf(mx, v[k]);
        mx = fmaxf(mx, __shfl_xor(mx, 1));
        mx = fmaxf(mx, __shfl_xor(mx, 2));
        float z = 0.f;
        #pragma unroll
        for (int k = 0; k < 16; k++) { v[k] = __expf(v[k]-mx); z += v[k]; }
        z += __shfl_xor(z, 1);
        z += __shfl_xor(z, 2);
        const float inv = 1.0f / z;
        __hip_bfloat16* S0 = (__hip_bfloat16*)(SM + OFF_S0);
        __hip_bfloat16* S1 = (__hip_bfloat16*)(SM + OFF_S1);
        __hip_bfloat16* G0 = (__hip_bfloat16*)(SM + OFF_G0);
        __hip_bfloat16* G1 = (__hip_bfloat16*)(SM + OFF_G1);
        #pragma unroll
        for (int k = 0; k < 16; k++) {
            const int j = q4*16 + k;
            const float t = v[k] * inv;
            const __hip_bfloat16 h0 = __float2bfloat16(t * pE[j]);
            const __hip_bfloat16 h1 = __float2bfloat16(t * pE[64 + j]);
            S0[r*MSTR + j] = h0;  S1[r*MSTR + j] = h1;
            G0[j*MSTR + r] = h0;  G1[j*MSTR + r] = h1;
        }
    }
    __syncthreads();

    // ---- phase 2: W_c[x][y] = (T_b2*T_b3)[y][x]; wave wv builds W_{c=wv} ----
    {
        const int c  = wv;
        const int b2 = c >> 1, b3 = c & 1;
        const __hip_bfloat16* X = (const __hip_bfloat16*)(SM + (b3 ? OFF_G1 : OFF_G0));
        const __hip_bfloat16* V = (const __hip_bfloat16*)(SM + (b2 ? OFF_S1 : OFF_S0));
        __hip_bfloat16* W = (__hip_bfloat16*)(SM + OFF_W) + c*(64*MSTR);
        #pragma unroll
        for (int xt = 0; xt < 4; xt++) {
            const bf16x8 a0 = *(const bf16x8*)(X + (xt*16+lr)*MSTR + g*8);
            const bf16x8 a1 = *(const bf16x8*)(X + (xt*16+lr)*MSTR + 32 + g*8);
            #pragma unroll
            for (int yb = 0; yb < 4; yb++) {
                const bf16x8 b0 = *(const bf16x8*)(V + (yb*16+lr)*MSTR + g*8);
                const bf16x8 b1 = *(const bf16x8*)(V + (yb*16+lr)*MSTR + 32 + g*8);
                f32x4 d = MFMA(a0, b0, zero);
                d = MFMA(a1, b1, d);
                const int ycol = yb*16 + lr, xb = xt*16 + g*4;
                W[(xb+0)*MSTR + ycol] = __float2bfloat16(d.x);
                W[(xb+1)*MSTR + ycol] = __float2bfloat16(d.y);
                W[(xb+2)*MSTR + ycol] = __float2bfloat16(d.z);
                W[(xb+3)*MSTR + ycol] = __float2bfloat16(d.w);
            }
        }
    }
    __syncthreads();

    // ---- phase 3: triples R_m = T_b1*(T_b2 T_b3), one at a time in OFF_R;
    //      this wg writes only ITS layout (fwd: transposed, bwd: plain). ----
    bf16x8 Afr[8][2];
    {
        __hip_bfloat16* R = (__hip_bfloat16*)(SM + OFF_R);
        #pragma unroll
        for (int m = 0; m < 8; m++) {
            const int b1 = m >> 2, c = m & 3;
            const __hip_bfloat16* X = (const __hip_bfloat16*)(SM + OFF_W) + c*(64*MSTR);
            const __hip_bfloat16* V = (const __hip_bfloat16*)(SM + (b1 ? OFF_S1 : OFF_S0));
            #pragma unroll
            for (int tt = 0; tt < 4; tt++) {
                const int t8 = wv*4 + tt;        // tile id 0..15
                const int xt = t8 >> 2, yb = t8 & 3;
                const bf16x8 a0 = *(const bf16x8*)(X + (xt*16+lr)*MSTR + g*8);
                const bf16x8 a1 = *(const bf16x8*)(X + (xt*16+lr)*MSTR + 32 + g*8);
                const bf16x8 b0 = *(const bf16x8*)(V + (yb*16+lr)*MSTR + g*8);
                const bf16x8 b1 = *(const bf16x8*)(V + (yb*16+lr)*MSTR + 32 + g*8);
                f32x4 d = MFMA(a0, b0, zero);
                d = MFMA(a1, b1, d);
                const int ycol = yb*16 + lr, xb = xt*16 + g*4;
                if (is_fwd) {                     // Rt[i][j] = R_m[j][i]
                    R[(xb+0)*MSTR + ycol] = __float2bfloat16(d.x);
                    R[(xb+1)*MSTR + ycol] = __float2bfloat16(d.y);
                    R[(xb+2)*MSTR + ycol] = __float2bfloat16(d.z);
                    R[(xb+3)*MSTR + ycol] = __float2bfloat16(d.w);
                } else {                          // Rp[j][i] = R_m[j][i]
                    union { __hip_bfloat16 hh[4]; uint2 u; } pk;
                    pk.hh[0] = __float2bfloat16(d.x);
                    pk.hh[1] = __float2bfloat16(d.y);
                    pk.hh[2] = __float2bfloat16(d.z);
                    pk.hh[3] = __float2bfloat16(d.w);
                    *(uint2*)(R + ycol*MSTR + xb) = pk.u;
                }
            }
            __syncthreads();
            Afr[m][0] = *(const bf16x8*)(R + (wv*16+lr)*MSTR + g*8);
            Afr[m][1] = *(const bf16x8*)(R + (wv*16+lr)*MSTR + 32 + g*8);
            __syncthreads();
        }
    }

    // ---- phase 4: ballot-pack y; build this wg's nibble stream ----
    unsigned long long* yball = (unsigned long long*)(SM + OFF_YBALL);
    #pragma unroll
    for (int q = 0; q < 4; q++) {
        const int row = wv*4 + q;
        const int* yr = y + (size_t)(R0 + row) * TLEN;
        #pragma unroll
        for (int w = 0; w < 16; w++) {
            const unsigned long long bal = __ballot(yr[w*64 + lane] != 0);
            if (lane == 0) yball[row*16 + w] = bal;
        }
    }
    __syncthreads();
    {
        unsigned long long* ys = (unsigned long long*)(SM + OFF_YS);
        const int c = tid & 15, slot = tid >> 4;
        if (slot < 11) {
            unsigned long long wd = 0ull;
            if (is_fwd) {
                for (int n = 0; n < 16; n++) {
                    const int i = slot*16 + n;
                    if (i < NF_IT) {
                        const int t1 = 3*i + 1;
                        const unsigned long long bA = (yball[c*16 + (t1>>6)] >> (t1 & 63)) & 1ull;
                        const unsigned long long bB = (yball[c*16 + ((t1+1)>>6)] >> ((t1+1) & 63)) & 1ull;
                        const unsigned long long bC = (yball[c*16 + ((t1+2)>>6)] >> ((t1+2) & 63)) & 1ull;
                        wd |= ((bA<<2) | (bB<<1) | bC) << (4*n);
                    }
                }
            } else {
                for (int n = 0; n < 16; n++) {
                    const int jj = slot*16 + n;
                    if (jj < NB_IT) {
                        const int t = 1021 - 3*jj;
                        const unsigned long long bA = (yball[c*16 + (t>>6)] >> (t & 63)) & 1ull;
                        const unsigned long long bB = (yball[c*16 + ((t+1)>>6)] >> ((t+1) & 63)) & 1ull;
                        const unsigned long long bC = (yball[c*16 + ((t+2)>>6)] >> ((t+2) & 63)) & 1ull;
                        wd |= ((bA<<2) | (bB<<1) | bC) << (4*n);
                    }
                }
            }
            ys[slot*16 + c] = wd;
        }
    }

    // ---- phase 5: init P[0]: alpha0 (fwd) or ones (bwd) ----
    __hip_bfloat16* P = (__hip_bfloat16*)(SM + OFF_P);
    {
        const int b = tid >> 4, s4 = (tid & 15) * 4;
        union { __hip_bfloat16 h[4]; uint2 u; } pk;
        if (is_fwd) {
            const int y0 = y[(size_t)(R0 + b) * TLEN];
            const float* pe = pE + y0*64;
            pk.h[0] = __float2bfloat16(piv[s4+0]*pe[s4+0]);
            pk.h[1] = __float2bfloat16(piv[s4+1]*pe[s4+1]);
            pk.h[2] = __float2bfloat16(piv[s4+2]*pe[s4+2]);
            pk.h[3] = __float2bfloat16(piv[s4+3]*pe[s4+3]);
        } else {
            pk.h[0] = pk.h[1] = pk.h[2] = pk.h[3] = __float2bfloat16(1.0f);
        }
        *(uint2*)(P + b*PSTR + s4) = pk.u;
    }
    __syncthreads();

    // ---- phase 6: main loop (independent per-wg barrier cadence) ----
    float lacc = 0.f;
    unsigned long long yw = 0ull;
    const unsigned long long* ys = (const unsigned long long*)(SM + OFF_YS);
    float* part = (float*)(SM + OFF_PART);
    const int nit = is_fwd ? NF_IT : NB_IT;
    f32x4 D = zero;
    int cur = 0;

    for (int j = 0; j < nit; j++) {
        if ((j & 15) == 0) yw = ys[(j>>4)*16 + lr];
        const int idx = (int)(yw & 7ull);
        yw >>= 4;

        const __hip_bfloat16* prow = P + cur*(16*PSTR) + lr*PSTR;
        const bf16x8 B0 = *(const bf16x8*)(prow + g*8);
        const bf16x8 B1 = *(const bf16x8*)(prow + 32 + g*8);

        f32x4 ca[8];
        #pragma unroll
        for (int m = 0; m < 8; m++) ca[m] = MFMA(Afr[m][0], B0, zero);
        #pragma unroll
        for (int m = 0; m < 8; m++) ca[m] = MFMA(Afr[m][1], B1, ca[m]);

        const bool s1 = idx & 1, s2 = idx & 2, s3 = idx & 4;
        const f32x4 t0 = s1 ? ca[1] : ca[0];
        const f32x4 t1 = s1 ? ca[3] : ca[2];
        const f32x4 t2 = s1 ? ca[5] : ca[4];
        const f32x4 t3 = s1 ? ca[7] : ca[6];
        const f32x4 u0 = s2 ? t1 : t0;
        const f32x4 u1 = s2 ? t3 : t2;
        f32x4 Dn = s3 ? u1 : u0;

        // deferred renorm, applied every 4th iter from sums taken at j-1
        if ((j & 3) == 0 && j > 0) {
            const float Sp = part[lr] + part[16+lr] + part[32+lr] + part[48+lr];
            lacc += __logf(Sp);
            Dn *= __builtin_amdgcn_rcpf(Sp);
        }
        if ((j & 3) == 3) {                    // column sums for next apply
            float p = Dn.x + Dn.y + Dn.z + Dn.w;
            p += __shfl_xor(p, 16);
            p += __shfl_xor(p, 32);
            if (lane < 16) part[wv*16 + lane] = p;
        }

        union { __hip_bfloat16 h[4]; uint2 u; } pk;
        pk.h[0] = __float2bfloat16(Dn.x);
        pk.h[1] = __float2bfloat16(Dn.y);
        pk.h[2] = __float2bfloat16(Dn.z);
        pk.h[3] = __float2bfloat16(Dn.w);
        *(uint2*)(P + (cur^1)*(16*PSTR) + lr*PSTR + wv*16 + g*4) = pk.u;
        __syncthreads();
        cur ^= 1;
        D = Dn;
    }

    // ---- write mid-state (bf16) + per-row log accumulator to ws ----
    {
        __hip_bfloat16* mid = (__hip_bfloat16*)(ws + (is_fwd ? WS_AM : WS_BM));
        union { __hip_bfloat16 h[4]; uint2 u; } pk;
        pk.h[0] = __float2bfloat16(D.x);
        pk.h[1] = __float2bfloat16(D.y);
        pk.h[2] = __float2bfloat16(D.z);
        pk.h[3] = __float2bfloat16(D.w);
        *(uint2*)(mid + (size_t)(R0 + lr)*64 + wv*16 + g*4) = pk.u;
        if (wv == 0 && lane < 16) {
            float* lw = (float*)(ws + (is_fwd ? WS_LF : WS_LB));
            lw[R0 + lane] = lacc;
        }
    }
}

// ---------------------------------------------------------------------------
// Epilogue: logprob[b] = laccF[b] + laccB[b] + log(alpha_mid[b] . beta_mid[b]);
// out = mean over batch.
// ---------------------------------------------------------------------------
__global__ __launch_bounds__(256) void hmm_epi(
    const unsigned char* __restrict__ ws, float* __restrict__ out)
{
    __shared__ float red[4];
    const int tid = threadIdx.x;
    const int row = blockIdx.x * 256 + tid;
    const __hip_bfloat16* am = (const __hip_bfloat16*)(ws + WS_AM) + (size_t)row * 64;
    const __hip_bfloat16* bm = (const __hip_bfloat16*)(ws + WS_BM) + (size_t)row * 64;
    float dot = 0.f;
    #pragma unroll
    for (int k = 0; k < 8; k++) {
        union { bf16x8 v; __hip_bfloat16 h[8]; } ua, ub;
        ua.v = *(const bf16x8*)(am + k*8);
        ub.v = *(const bf16x8*)(bm + k*8);
        #pragma unroll
        for (int e = 0; e < 8; e++)
            dot += __bfloat162float(ua.h[e]) * __bfloat162float(ub.h[e]);
    }
    const float* lF = (const float*)(ws + WS_LF);
    const float* lB = (const float*)(ws + WS_LB);
    float lp = lF[row] + lB[row] + __logf(dot);
    #pragma unroll
    for (int d = 1; d < 64; d <<= 1) lp += __shfl_xor(lp, d);
    if ((tid & 63) == 0) red[tid >> 6] = lp;
    __syncthreads();
    if (tid == 0)
        atomicAdd(out, (red[0]+red[1]+red[2]+red[3]) * (1.0f / BATCH));
}

// ---------------------------------------------------------------------------
extern "C" void kernel_launch(void* const* d_in, const int* in_sizes, int n_in,
                              void* d_out, int out_size, void* d_ws, size_t ws_size,
                              hipStream_t stream) {
    const int*   y  = (const int*)  d_in[0];
    const float* T  = (const float*)d_in[1];
    const float* E  = (const float*)d_in[2];
    const float* Pi = (const float*)d_in[3];
    float* out = (float*)d_out;
    unsigned char* ws = (unsigned char*)d_ws;
    (void)ws_size;

    hipMemsetAsync(out, 0, sizeof(float), stream);
    hipLaunchKernelGGL(hmm_chain, dim3(2*BATCH/16), dim3(256), 0, stream, y, T, E, Pi, ws);
    hipLaunchKernelGGL(hmm_epi,   dim3(BATCH/256),  dim3(256), 0, stream, ws, out);
}